// Round 9
// baseline (1364.573 us; speedup 1.0000x reference)
//
#include <hip/hip_runtime.h>
#include <cstdint>
#include <cstddef>

#define NB 64      // batch
#define LN 48      // buffer length
#define DN 256     // hidden dim
#define TKN 128    // tracker dim
#define TN 95      // steps
#define RMAX 48    // max reduces per batch
#define GA 512     // 4*TK
#define GR 1280    // 5*D
#define NWG 256
#define NT 512
#define NCL 8      // clusters (one per XCD by wg&7 round-robin heuristic)
#define CM 32      // members per cluster

__device__ __forceinline__ float sigf(float x) { return 1.0f / (1.0f + expf(-x)); }

// coherent (sc1) scalar access — bypasses non-coherent per-XCD L2 (verified r4-r8)
__device__ __forceinline__ float cohLd(const float* p) {
    return __hip_atomic_load(p, __ATOMIC_RELAXED, __HIP_MEMORY_SCOPE_AGENT);
}
__device__ __forceinline__ void cohSt(float* p, float v) {
    __hip_atomic_store(p, v, __ATOMIC_RELAXED, __HIP_MEMORY_SCOPE_AGENT);
}
__device__ __forceinline__ unsigned cohLdU(const unsigned* p) {
    return __hip_atomic_load(p, __ATOMIC_RELAXED, __HIP_MEMORY_SCOPE_AGENT);
}
__device__ __forceinline__ void cohStU(unsigned* p, unsigned v) {
    __hip_atomic_store(p, v, __ATOMIC_RELAXED, __HIP_MEMORY_SCOPE_AGENT);
}

// intra-cluster all-observe barrier: 32 members, each stores its slot then
// threads 0..31 poll all member slots directly (no watcher/flag hops).
// __syncthreads() drains vmcnt(0) before the arrival store (scheme verified r4-r8).
__device__ __forceinline__ void csync(unsigned* slots, int cl, int mem, unsigned& ph) {
    __syncthreads();
    ph += 1;
    if (threadIdx.x == 0) cohStU(&slots[(cl * CM + mem) * 16], ph);
    if (threadIdx.x < CM) {
        while (cohLdU(&slots[(cl * CM + threadIdx.x) * 16]) < ph)
            __builtin_amdgcn_s_sleep(1);
    }
    __syncthreads();
}

// ---------------- schedule builder (verified r1-r8) -------------------------
__global__ void k_sched(const int* __restrict__ trans,
                        int* __restrict__ tbcode, int* __restrict__ s1code,
                        int* __restrict__ s2code, int* __restrict__ wkA,
                        int* __restrict__ fcode, int* __restrict__ anyredc) {
    __shared__ int tg[NB][LN];
    int b = threadIdx.x;
    if (b >= NB) return;
    for (int i = 0; i < LN; ++i) tg[b][i] = -1;
    int sp = 0, bp = 0, k = 0;
    for (int t = 0; t < TN; ++t) {
        int tr = trans[b * TN + t];
        int shift = (tr == 0);
        int tb = (bp < LN) ? bp : -1;
        tbcode[t * NB + b] = tb;
        int i1 = sp - 1; if (i1 < 0) i1 = 0; if (i1 > LN - 1) i1 = LN - 1;
        int i2 = sp - 2; if (i2 < 0) i2 = 0; if (i2 > LN - 1) i2 = LN - 1;
        s1code[t * NB + b] = (sp >= 1) ? tg[b][i1] : -1;
        s2code[t * NB + b] = (sp >= 2) ? tg[b][i2] : -1;
        int wk_t;
        if (shift) {
            wk_t = -1;
            if (sp >= 0 && sp < LN) tg[b][sp] = tb;
            sp = sp + 1;
            bp = bp + 1;
        } else {
            wk_t = k;
            int pos = sp - 2; if (pos < 0) pos = 0;
            if (pos < LN) tg[b][pos] = 1000 + k;
            k++;
            sp = sp - 1; if (sp < 0) sp = 0;
        }
        wkA[t * NB + b] = wk_t;
        unsigned long long m = __ballot(wk_t >= 0);
        if (b < NCL) {
            unsigned grp = (unsigned)((m >> (b * 8)) & 0xFFull);
            anyredc[b * TN + t] = grp ? 1 : 0;
        }
    }
    int fi = sp - 1; if (fi < 0) fi = 0; if (fi > LN - 1) fi = LN - 1;
    fcode[b] = tg[b][fi];
}

// ---- P1 pack: WAc[cg32][q224][c16][kq4]; packed col p=cg*16+c = j*4+gate ----
__global__ __launch_bounds__(256) void k_pack_a(
    const float* __restrict__ Wb, const float* __restrict__ W1,
    const float* __restrict__ W2, const float* __restrict__ Wl,
    const float* __restrict__ blv,
    float* __restrict__ WAc, float* __restrict__ blA) {
    int idx = blockIdx.x * 256 + threadIdx.x;
    if (idx < 32 * 224 * 64) {
        int cg = idx / (224 * 64);
        int r = idx % (224 * 64);
        int q = r >> 6, rr = r & 63;
        int c = rr >> 2, kq = rr & 3;
        int p = cg * 16 + c;
        int j = p >> 2, qd = p & 3;
        int sc = qd * 128 + j;
        int k = q * 4 + kq;
        float v;
        if (k < 256)      v = Wb[(size_t)k * GA + sc];
        else if (k < 512) v = W1[(size_t)(k - 256) * GA + sc];
        else if (k < 768) v = W2[(size_t)(k - 512) * GA + sc];
        else              v = Wl[(size_t)(k - 768) * GA + sc];
        WAc[idx] = v;
    }
    if (idx < 512) {
        int j = idx >> 2, qd = idx & 3;
        blA[idx] = blv[qd * 128 + j];
    }
}

// ---- P2 pack: WBc[jsl32][q160][slot64][kq4]; slot=jloc*8+g (g<5 real) -------
__global__ __launch_bounds__(256) void k_pack_b(
    const float* __restrict__ WLm, const float* __restrict__ WRm,
    const float* __restrict__ WTm, float* __restrict__ WBc) {
    int idx = blockIdx.x * 256 + threadIdx.x;
    if (idx >= 32 * 160 * 256) return;
    int jsl = idx / (160 * 256);
    int r = idx % (160 * 256);
    int q = r >> 8, rr = r & 255;
    int slot = rr >> 2, kq = rr & 3;
    int jl = slot >> 3, g = slot & 7;
    int k = q * 4 + kq;
    float v = 0.f;
    if (g < 5) {
        int sc = g * 256 + jsl * 8 + jl;
        if (k < 256)      v = WLm[(size_t)k * GR + sc];
        else if (k < 512) v = WRm[(size_t)(k - 256) * GR + sc];
        else              v = WTm[(size_t)(k - 512) * GR + sc];
    }
    WBc[idx] = v;
}

// ---------------- persistent clustered full-scan kernel ---------------------
__global__ __launch_bounds__(NT, 1) void k_spinn(
    const float* __restrict__ bufh, const float* __restrict__ bufc,
    const float* __restrict__ WAc, const float* __restrict__ blA,
    const float* __restrict__ WBc, const float* __restrict__ bLv,
    const int* __restrict__ tbcode, const int* __restrict__ s1code,
    const int* __restrict__ s2code, const int* __restrict__ wkA,
    const int* __restrict__ fcode, const int* __restrict__ anyredc,
    float* __restrict__ th, float* __restrict__ tc,
    float* __restrict__ redh, float* __restrict__ redc,
    unsigned* __restrict__ slots, float* __restrict__ out) {
    const int wg = blockIdx.x;
    const int tid = threadIdx.x;
    const int cl = wg & 7;                 // cluster (XCD-pinned heuristic)
    const int mem = wg >> 3;               // member 0..31 = colgroup / jsl
    const int b0 = cl * 8;                 // cluster's batch base
    unsigned ph = 0;

    __shared__ union {
        struct { float4 xs4[8][224]; float part1[32][16][9]; float gsum[16][8]; } p1;
        struct { float4 xs2q[8][160]; float part2[8][64][9]; float gsum2[64][8]; } p2;
    } sm;

    for (int t = 0; t < TN; ++t) {
        const int par = t & 1;
        const bool red = anyredc[cl * TN + t] != 0;

        // ========== stage P1: xs[8][896] as 1792 float4 groups ==========
        for (int g = tid; g < 1792; g += NT) {
            int row = g / 224, k4 = g - row * 224, k0 = k4 * 4;
            int b = b0 + row;
            float4 v = {0.f, 0.f, 0.f, 0.f};
            if (k0 < 256) {
                int c = tbcode[t * NB + b];
                if (c >= 0) v = *(const float4*)&bufh[((size_t)b * LN + c) * DN + k0];
            } else if (k0 < 512) {
                int c = s1code[t * NB + b];
                int kk = k0 - 256;
                if (c >= 1000) {
                    const float* p = &redh[((size_t)(c - 1000) * NB + b) * DN + kk];
                    v.x = cohLd(p); v.y = cohLd(p + 1); v.z = cohLd(p + 2); v.w = cohLd(p + 3);
                } else if (c >= 0) v = *(const float4*)&bufh[((size_t)b * LN + c) * DN + kk];
            } else if (k0 < 768) {
                int c = s2code[t * NB + b];
                int kk = k0 - 512;
                if (c >= 1000) {
                    const float* p = &redh[((size_t)(c - 1000) * NB + b) * DN + kk];
                    v.x = cohLd(p); v.y = cohLd(p + 1); v.z = cohLd(p + 2); v.w = cohLd(p + 3);
                } else if (c >= 0) v = *(const float4*)&bufh[((size_t)b * LN + c) * DN + kk];
            } else {
                const float* p = &th[((size_t)par * NB + b) * TKN + (k0 - 768)];
                v.x = cohLd(p); v.y = cohLd(p + 1); v.z = cohLd(p + 2); v.w = cohLd(p + 3);
            }
            sm.p1.xs4[row][k4] = v;
        }
        __syncthreads();

        // ========== P1 GEMM: 16 cols x 32 kslices; 1KB contiguous/wave ==========
        {
            int c = tid & 15, ks = tid >> 4;
            float acc[8];
            #pragma unroll
            for (int b = 0; b < 8; ++b) acc[b] = 0.f;
            const float4* wp = (const float4*)WBc;  // placeholder silence
            (void)wp;
            const float4* wa = (const float4*)WAc + (size_t)mem * 224 * 16 + c;
            #pragma unroll
            for (int i = 0; i < 7; ++i) {
                int q = ks + 32 * i;
                float4 wq = wa[(size_t)q * 16];
                #pragma unroll
                for (int b = 0; b < 8; ++b) {
                    float4 xv = sm.p1.xs4[b][q];
                    acc[b] += xv.x * wq.x + xv.y * wq.y + xv.z * wq.z + xv.w * wq.w;
                }
            }
            #pragma unroll
            for (int b = 0; b < 8; ++b) sm.p1.part1[ks][c][b] = acc[b];
        }
        __syncthreads();
        // ---- P1 reduce over 32 kslices ----
        if (tid < 128) {
            int c = tid >> 3, b = tid & 7;
            float s = 0.f;
            #pragma unroll
            for (int ks = 0; ks < 32; ++ks) s += sm.p1.part1[ks][c][b];
            if (t > 0) s += blA[mem * 16 + c];
            sm.p1.gsum[c][b] = s;
        }
        __syncthreads();
        // ---- tracker LSTM (4 j x 8 b per WG) ----
        if (tid < 32) {
            int jl = tid >> 3, b = tid & 7;
            int bb = b0 + b;
            int j = mem * 4 + jl;
            float a  = sm.p1.gsum[jl * 4 + 0][b];
            float i_ = sm.p1.gsum[jl * 4 + 1][b];
            float f  = sm.p1.gsum[jl * 4 + 2][b];
            float o  = sm.p1.gsum[jl * 4 + 3][b];
            float tco = tc[((size_t)par * NB + bb) * TKN + j];       // owner-stable
            float c2v = tanhf(a) * sigf(i_) + sigf(f) * tco;
            float h2 = sigf(o) * tanhf(c2v);
            tc[((size_t)(par ^ 1) * NB + bb) * TKN + j] = c2v;       // owner-stable
            cohSt(&th[((size_t)(par ^ 1) * NB + bb) * TKN + j], h2); // cluster-wide
        }
        csync(slots, cl, mem, ph);   // sync A: th2 visible within cluster

        if (red) {
            // ========== stage P2: xs2[8][640] as 1280 float4 groups ==========
            const int par2 = par ^ 1;
            for (int g = tid; g < 1280; g += NT) {
                int row = g / 160, k4 = g - row * 160, k0 = k4 * 4;
                int b = b0 + row;
                float4 v = {0.f, 0.f, 0.f, 0.f};
                if (k0 < 256) {
                    int c = s2code[t * NB + b];
                    if (c >= 1000) {
                        const float* p = &redh[((size_t)(c - 1000) * NB + b) * DN + k0];
                        v.x = cohLd(p); v.y = cohLd(p + 1); v.z = cohLd(p + 2); v.w = cohLd(p + 3);
                    } else if (c >= 0) v = *(const float4*)&bufh[((size_t)b * LN + c) * DN + k0];
                } else if (k0 < 512) {
                    int c = s1code[t * NB + b];
                    int kk = k0 - 256;
                    if (c >= 1000) {
                        const float* p = &redh[((size_t)(c - 1000) * NB + b) * DN + kk];
                        v.x = cohLd(p); v.y = cohLd(p + 1); v.z = cohLd(p + 2); v.w = cohLd(p + 3);
                    } else if (c >= 0) v = *(const float4*)&bufh[((size_t)b * LN + c) * DN + kk];
                } else {
                    const float* p = &th[((size_t)par2 * NB + b) * TKN + (k0 - 512)];
                    v.x = cohLd(p); v.y = cohLd(p + 1); v.z = cohLd(p + 2); v.w = cohLd(p + 3);
                }
                sm.p2.xs2q[row][k4] = v;
            }
            __syncthreads();
            // ========== P2 GEMM: 64 slots x 8 ksq; 1KB contiguous/wave ==========
            {
                int slot = tid & 63, ksq = tid >> 6;
                float acc[8];
                #pragma unroll
                for (int b = 0; b < 8; ++b) acc[b] = 0.f;
                const float4* wb = (const float4*)WBc + (size_t)mem * 160 * 64 + slot;
                #pragma unroll 4
                for (int i = 0; i < 20; ++i) {
                    int q = ksq + 8 * i;
                    float4 wq = wb[(size_t)q * 64];
                    #pragma unroll
                    for (int b = 0; b < 8; ++b) {
                        float4 xv = sm.p2.xs2q[b][q];
                        acc[b] += xv.x * wq.x + xv.y * wq.y + xv.z * wq.z + xv.w * wq.w;
                    }
                }
                #pragma unroll
                for (int b = 0; b < 8; ++b) sm.p2.part2[ksq][slot][b] = acc[b];
            }
            __syncthreads();
            // ---- P2 reduce over 8 ksq ----
            {
                int slot = tid >> 3, b = tid & 7;
                float s = 0.f;
                #pragma unroll
                for (int ksq = 0; ksq < 8; ++ksq) s += sm.p2.part2[ksq][slot][b];
                sm.p2.gsum2[slot][b] = s;
            }
            __syncthreads();
            // ---- TreeLSTM (8 j x 8 b per WG) ----
            if (tid < 64) {
                int jl = tid >> 3, b = tid & 7;
                int bb = b0 + b;
                int wk = wkA[t * NB + bb];
                if (wk >= 0) {
                    int j = mem * 8 + jl;
                    float ga  = sm.p2.gsum2[jl * 8 + 0][b] + bLv[0 * 256 + j];
                    float gi  = sm.p2.gsum2[jl * 8 + 1][b] + bLv[1 * 256 + j];
                    float gf1 = sm.p2.gsum2[jl * 8 + 2][b] + bLv[2 * 256 + j];
                    float gf2 = sm.p2.gsum2[jl * 8 + 3][b] + bLv[3 * 256 + j];
                    float go  = sm.p2.gsum2[jl * 8 + 4][b] + bLv[4 * 256 + j];
                    int c1 = s1code[t * NB + bb], c2 = s2code[t * NB + bb];
                    float s2cv = (c2 == -1) ? 0.f
                                : ((c2 >= 1000) ? redc[((size_t)(c2 - 1000) * NB + bb) * DN + j]
                                                : bufc[((size_t)bb * LN + c2) * DN + j]);
                    float s1cv = (c1 == -1) ? 0.f
                                : ((c1 >= 1000) ? redc[((size_t)(c1 - 1000) * NB + bb) * DN + j]
                                                : bufc[((size_t)bb * LN + c1) * DN + j]);
                    float cc = tanhf(ga) * sigf(gi) + sigf(gf1) * s2cv + sigf(gf2) * s1cv;
                    float hh = sigf(go) * tanhf(cc);
                    cohSt(&redh[((size_t)wk * NB + bb) * DN + j], hh);   // cluster-wide
                    redc[((size_t)wk * NB + bb) * DN + j] = cc;          // owner-stable
                }
            }
            csync(slots, cl, mem, ph);   // sync B: redh visible within cluster
        }
    }

    // ===== final output: owner (bb, j-slice) writes; all own data =====
    if (tid < 64) {
        int jl = tid >> 3, b = tid & 7;
        int bb = b0 + b;
        int j = mem * 8 + jl;
        int c = fcode[bb];
        float h = 0.f, cv = 0.f;
        if (c >= 1000) {
            h  = cohLd(&redh[((size_t)(c - 1000) * NB + bb) * DN + j]);
            cv = redc[((size_t)(c - 1000) * NB + bb) * DN + j];
        } else if (c >= 0) {
            h  = bufh[((size_t)bb * LN + c) * DN + j];
            cv = bufc[((size_t)bb * LN + c) * DN + j];
        }
        out[(size_t)bb * 2 * DN + j]      = h;
        out[(size_t)bb * 2 * DN + DN + j] = cv;
    }
}

extern "C" void kernel_launch(void* const* d_in, const int* in_sizes, int n_in,
                              void* d_out, int out_size, void* d_ws, size_t ws_size,
                              hipStream_t stream) {
    const float* bufh = (const float*)d_in[0];
    const float* bufc = (const float*)d_in[1];
    const float* Wb   = (const float*)d_in[2];
    const float* W1   = (const float*)d_in[3];
    const float* W2   = (const float*)d_in[4];
    const float* Wl   = (const float*)d_in[5];
    const float* blv  = (const float*)d_in[6];
    const float* WLm  = (const float*)d_in[7];
    const float* bLv  = (const float*)d_in[8];
    const float* WR   = (const float*)d_in[9];
    const float* WT   = (const float*)d_in[10];
    const int* trans  = (const int*)d_in[11];
    float* out = (float*)d_out;

    char* p = (char*)d_ws;
    auto carve = [&](size_t bytes) -> char* {
        char* r = p;
        p += (bytes + 255) & ~(size_t)255;
        return r;
    };
    int* tbcode = (int*)carve((size_t)TN * NB * 4);
    int* s1code = (int*)carve((size_t)TN * NB * 4);
    int* s2code = (int*)carve((size_t)TN * NB * 4);
    int* wkA    = (int*)carve((size_t)TN * NB * 4);
    int* fcode  = (int*)carve((size_t)NB * 4);
    int* anyredc= (int*)carve((size_t)NCL * TN * 4);
    float* th   = (float*)carve((size_t)2 * NB * TKN * 4);
    float* tc   = (float*)carve((size_t)2 * NB * TKN * 4);
    float* redh = (float*)carve((size_t)RMAX * NB * DN * 4);
    float* redc = (float*)carve((size_t)RMAX * NB * DN * 4);
    float* WAc  = (float*)carve((size_t)32 * 224 * 64 * 4);
    float* blA  = (float*)carve((size_t)512 * 4);
    float* WBc  = (float*)carve((size_t)32 * 160 * 256 * 4);
    unsigned* slots = (unsigned*)carve((size_t)NCL * CM * 16 * 4);

    hipMemsetAsync(th, 0, (size_t)2 * NB * TKN * 4, stream);
    hipMemsetAsync(tc, 0, (size_t)2 * NB * TKN * 4, stream);
    hipMemsetAsync(slots, 0, (size_t)NCL * CM * 16 * 4, stream);

    k_sched<<<1, 64, 0, stream>>>(trans, tbcode, s1code, s2code, wkA, fcode, anyredc);
    k_pack_a<<<(32 * 224 * 64 + 255) / 256, 256, 0, stream>>>(Wb, W1, W2, Wl, blv, WAc, blA);
    k_pack_b<<<(32 * 160 * 256 + 255) / 256, 256, 0, stream>>>(WLm, WR, WT, WBc);
    k_spinn<<<NWG, NT, 0, stream>>>(bufh, bufc, WAc, blA, WBc, bLv,
                                    tbcode, s1code, s2code, wkA, fcode, anyredc,
                                    th, tc, redh, redc, slots, out);
}

// Round 10
// 921.243 us; speedup vs baseline: 1.4812x; 1.4812x over previous
//
#include <hip/hip_runtime.h>
#include <cstdint>
#include <cstddef>

#define NB 64      // batch
#define LN 48      // buffer length
#define DN 256     // hidden dim
#define TKN 128    // tracker dim
#define TN 95      // steps
#define RMAX 48    // max reduces per batch
#define GA 512     // 4*TK
#define GR 1280    // 5*D
#define NWG 256
#define NT 512

__device__ __forceinline__ float sigf(float x) { return 1.0f / (1.0f + expf(-x)); }

__device__ __forceinline__ float bf2f(unsigned u16) {
    unsigned x = u16 << 16;
    return __builtin_bit_cast(float, x);
}
__device__ __forceinline__ unsigned short f2bf(float f) {
    unsigned x = __builtin_bit_cast(unsigned, f);
    unsigned r = (x + 0x7FFFu + ((x >> 16) & 1u)) >> 16;
    return (unsigned short)r;
}

// coherent (sc1) scalar access — bypasses non-coherent per-XCD L2 (verified r4-r8)
__device__ __forceinline__ float cohLd(const float* p) {
    return __hip_atomic_load(p, __ATOMIC_RELAXED, __HIP_MEMORY_SCOPE_AGENT);
}
__device__ __forceinline__ void cohSt(float* p, float v) {
    __hip_atomic_store(p, v, __ATOMIC_RELAXED, __HIP_MEMORY_SCOPE_AGENT);
}
__device__ __forceinline__ unsigned cohLdU(const unsigned* p) {
    return __hip_atomic_load(p, __ATOMIC_RELAXED, __HIP_MEMORY_SCOPE_AGENT);
}
__device__ __forceinline__ void cohStU(unsigned* p, unsigned v) {
    __hip_atomic_store(p, v, __ATOMIC_RELAXED, __HIP_MEMORY_SCOPE_AGENT);
}

// contention-free grid barrier (verified r6-r8)
__device__ __forceinline__ void gbar(unsigned* slots, unsigned* flag, unsigned& ph) {
    __syncthreads();
    ph += 1;
    if (blockIdx.x == 0) {
        if (threadIdx.x == 0) cohStU(&slots[0], ph);
        if (threadIdx.x < NWG) {
            while (cohLdU(&slots[threadIdx.x * 16]) < ph)
                __builtin_amdgcn_s_sleep(1);
        }
        __syncthreads();
        if (threadIdx.x == 0) cohStU(flag, ph);
        asm volatile("" ::: "memory");
        __syncthreads();
    } else {
        if (threadIdx.x == 0) {
            cohStU(&slots[blockIdx.x * 16], ph);
            while (cohLdU(flag) < ph)
                __builtin_amdgcn_s_sleep(1);
        }
        asm volatile("" ::: "memory");
        __syncthreads();
    }
}

// ---------------- schedule builder (verified r1-r8) -------------------------
__global__ void k_sched(const int* __restrict__ trans,
                        int* __restrict__ tbcode, int* __restrict__ s1code,
                        int* __restrict__ s2code, int* __restrict__ wkA,
                        int* __restrict__ fcode, int* __restrict__ anyred) {
    __shared__ int tg[NB][LN];
    int b = threadIdx.x;
    if (b >= NB) return;
    for (int i = 0; i < LN; ++i) tg[b][i] = -1;
    int sp = 0, bp = 0, k = 0;
    for (int t = 0; t < TN; ++t) {
        int tr = trans[b * TN + t];
        int shift = (tr == 0);
        int tb = (bp < LN) ? bp : -1;
        tbcode[t * NB + b] = tb;
        int i1 = sp - 1; if (i1 < 0) i1 = 0; if (i1 > LN - 1) i1 = LN - 1;
        int i2 = sp - 2; if (i2 < 0) i2 = 0; if (i2 > LN - 1) i2 = LN - 1;
        s1code[t * NB + b] = (sp >= 1) ? tg[b][i1] : -1;
        s2code[t * NB + b] = (sp >= 2) ? tg[b][i2] : -1;
        int wk_t;
        if (shift) {
            wk_t = -1;
            if (sp >= 0 && sp < LN) tg[b][sp] = tb;
            sp = sp + 1;
            bp = bp + 1;
        } else {
            wk_t = k;
            int pos = sp - 2; if (pos < 0) pos = 0;
            if (pos < LN) tg[b][pos] = 1000 + k;
            k++;
            sp = sp - 1; if (sp < 0) sp = 0;
        }
        wkA[t * NB + b] = wk_t;
        unsigned long long m = __ballot(wk_t >= 0);
        if (b == 0) anyred[t] = (m != 0ull) ? 1 : 0;
    }
    int fi = sp - 1; if (fi < 0) fi = 0; if (fi > LN - 1) fi = LN - 1;
    fcode[b] = tg[b][fi];
}

// ---- P1 pack (bf16): WAb[slice8][k896][64 cols]; packed col p = j*4+gate ----
__global__ __launch_bounds__(256) void k_pack_a(
    const float* __restrict__ Wb, const float* __restrict__ W1,
    const float* __restrict__ W2, const float* __restrict__ Wl,
    const float* __restrict__ blv,
    unsigned short* __restrict__ WAb, float* __restrict__ blA) {
    int idx = blockIdx.x * 256 + threadIdx.x;
    if (idx < 8 * 896 * 64) {
        int s = idx / (896 * 64);
        int r = idx % (896 * 64);
        int k = r >> 6, c = r & 63;
        int p = s * 64 + c;
        int j = p >> 2, q = p & 3;
        int sc = q * 128 + j;
        float v;
        if (k < 256)      v = Wb[(size_t)k * GA + sc];
        else if (k < 512) v = W1[(size_t)(k - 256) * GA + sc];
        else if (k < 768) v = W2[(size_t)(k - 512) * GA + sc];
        else              v = Wl[(size_t)(k - 768) * GA + sc];
        WAb[idx] = f2bf(v);
    }
    if (idx < 512) {
        int j = idx >> 2, q = idx & 3;
        blA[idx] = blv[q * 128 + j];
    }
}

// ---- P2 pack (bf16): WBb[slice16][k640][jj16*8slots]; slot g<5 real ---------
__global__ __launch_bounds__(256) void k_pack_b(
    const float* __restrict__ WLm, const float* __restrict__ WRm,
    const float* __restrict__ WTm, unsigned short* __restrict__ WBb) {
    int idx = blockIdx.x * 256 + threadIdx.x;
    if (idx >= 16 * 640 * 128) return;
    int s = idx / (640 * 128);
    int r = idx % (640 * 128);
    int k = r >> 7, cc = r & 127;
    int jj = cc >> 3, g = cc & 7;
    float v = 0.f;
    if (g < 5) {
        int sc = g * 256 + s * 16 + jj;
        if (k < 256)      v = WLm[(size_t)k * GR + sc];
        else if (k < 512) v = WRm[(size_t)(k - 256) * GR + sc];
        else              v = WTm[(size_t)(k - 512) * GR + sc];
    }
    WBb[idx] = f2bf(v);
}

// ---------------- persistent full-scan kernel (r8 structure, bf16 weights) --
__global__ __launch_bounds__(NT, 1) void k_spinn(
    const float* __restrict__ bufh, const float* __restrict__ bufc,
    const unsigned short* __restrict__ WAb, const float* __restrict__ blA,
    const unsigned short* __restrict__ WBb, const float* __restrict__ bLv,
    const int* __restrict__ tbcode, const int* __restrict__ s1code,
    const int* __restrict__ s2code, const int* __restrict__ wkA,
    const int* __restrict__ fcode, const int* __restrict__ anyred,
    float* __restrict__ th, float* __restrict__ tc,
    float* __restrict__ redh, float* __restrict__ redc,
    unsigned* __restrict__ slots, unsigned* __restrict__ flag,
    float* __restrict__ out) {
    const int wg = blockIdx.x;
    const int tid = threadIdx.x;
    const int lane = tid & 63;
    const int w = tid >> 6;                 // 8 waves
    unsigned ph = 0;

    const int xcd = wg & 7;
    const int u = wg >> 3;                  // 0..31
    const int jg = xcd;                     // P1 64-col slice (114KB bf16, L2/XCD)
    const int bg1 = u;                      // P1: 2 b
    const int bg2 = u >> 1;                 // P2: 4 b
    const int jgw = (u & 1) + 2 * xcd;      // P2 slice (160KB bf16; 2/XCD)

    __shared__ float xs[2][896];            // P1 input
    __shared__ float part1[2][64][33];      // P1 partials (2-way bank max)
    __shared__ float gsum[2][64];
    __shared__ float xs2[4][512];           // P2 s-part input
    __shared__ float part2[16][16][21];     // P2 partials, padded
    __shared__ float gsum2[4][5][16];
    __shared__ float xst[4][128];           // th2 for WT part

    for (int t = 0; t < TN; ++t) {
        const int par = t & 1;
        const bool red = anyred[t] != 0;

        // ============ stage: P1 xs (448 f4) + P2s xs2 (512 f4) ============
        int ngroups = red ? 960 : 448;
        for (int g = tid; g < ngroups; g += NT) {
            if (g < 448) {
                int row = g & 1, k0 = (g >> 1) * 4;
                int b = bg1 * 2 + row;
                float4 v = {0.f, 0.f, 0.f, 0.f};
                if (k0 < 256) {
                    int c = tbcode[t * NB + b];
                    if (c >= 0) v = *(const float4*)&bufh[((size_t)b * LN + c) * DN + k0];
                } else if (k0 < 512) {
                    int c = s1code[t * NB + b];
                    int kk = k0 - 256;
                    if (c >= 1000) {
                        const float* p = &redh[((size_t)(c - 1000) * NB + b) * DN + kk];
                        v.x = cohLd(p); v.y = cohLd(p + 1); v.z = cohLd(p + 2); v.w = cohLd(p + 3);
                    } else if (c >= 0) v = *(const float4*)&bufh[((size_t)b * LN + c) * DN + kk];
                } else if (k0 < 768) {
                    int c = s2code[t * NB + b];
                    int kk = k0 - 512;
                    if (c >= 1000) {
                        const float* p = &redh[((size_t)(c - 1000) * NB + b) * DN + kk];
                        v.x = cohLd(p); v.y = cohLd(p + 1); v.z = cohLd(p + 2); v.w = cohLd(p + 3);
                    } else if (c >= 0) v = *(const float4*)&bufh[((size_t)b * LN + c) * DN + kk];
                } else {
                    const float* p = &th[((size_t)par * NB + b) * TKN + (k0 - 768)];
                    v.x = cohLd(p); v.y = cohLd(p + 1); v.z = cohLd(p + 2); v.w = cohLd(p + 3);
                }
                *(float4*)&xs[row][k0] = v;
            } else {
                int g2 = g - 448;
                int row = g2 & 3, k0 = (g2 >> 2) * 4;
                int b = bg2 * 4 + row;
                float4 v = {0.f, 0.f, 0.f, 0.f};
                if (k0 < 256) {
                    int c = s2code[t * NB + b];
                    if (c >= 1000) {
                        const float* p = &redh[((size_t)(c - 1000) * NB + b) * DN + k0];
                        v.x = cohLd(p); v.y = cohLd(p + 1); v.z = cohLd(p + 2); v.w = cohLd(p + 3);
                    } else if (c >= 0) v = *(const float4*)&bufh[((size_t)b * LN + c) * DN + k0];
                } else {
                    int c = s1code[t * NB + b];
                    int kk = k0 - 256;
                    if (c >= 1000) {
                        const float* p = &redh[((size_t)(c - 1000) * NB + b) * DN + kk];
                        v.x = cohLd(p); v.y = cohLd(p + 1); v.z = cohLd(p + 2); v.w = cohLd(p + 3);
                    } else if (c >= 0) v = *(const float4*)&bufh[((size_t)b * LN + c) * DN + kk];
                }
                *(float4*)&xs2[row][k0] = v;
            }
        }
        __syncthreads();

        // ============ concurrent GEMMs: waves 0-3 P1, waves 4-7 P2s ============
        float acc[5][4];   // P2 accumulators live across barrier A in registers
        if (w < 4) {
            // lane: c8 = col octet (8 bf16 = 16B load), kq = k-phase
            int c8 = lane & 7, kq = lane >> 3;
            int kbase = w * 224;
            const uint4* wp = (const uint4*)WAb + ((size_t)(jg * 896 + kbase + kq) * 8) + c8;
            float a0[8], a1[8];
            #pragma unroll
            for (int cc = 0; cc < 8; ++cc) { a0[cc] = 0.f; a1[cc] = 0.f; }
            #pragma unroll 4
            for (int i = 0; i < 28; ++i) {
                uint4 wv = wp[(size_t)i * 64];          // wave: 1KB contiguous
                int k = kbase + kq + i * 8;
                float x0 = xs[0][k], x1 = xs[1][k];
                float wf0 = bf2f(wv.x & 0xFFFF), wf1 = bf2f(wv.x >> 16);
                float wf2 = bf2f(wv.y & 0xFFFF), wf3 = bf2f(wv.y >> 16);
                float wf4 = bf2f(wv.z & 0xFFFF), wf5 = bf2f(wv.z >> 16);
                float wf6 = bf2f(wv.w & 0xFFFF), wf7 = bf2f(wv.w >> 16);
                a0[0] += x0 * wf0; a1[0] += x1 * wf0;
                a0[1] += x0 * wf1; a1[1] += x1 * wf1;
                a0[2] += x0 * wf2; a1[2] += x1 * wf2;
                a0[3] += x0 * wf3; a1[3] += x1 * wf3;
                a0[4] += x0 * wf4; a1[4] += x1 * wf4;
                a0[5] += x0 * wf5; a1[5] += x1 * wf5;
                a0[6] += x0 * wf6; a1[6] += x1 * wf6;
                a0[7] += x0 * wf7; a1[7] += x1 * wf7;
            }
            int ks = w * 8 + kq;
            #pragma unroll
            for (int cc = 0; cc < 8; ++cc) {
                part1[0][c8 * 8 + cc][ks] = a0[cc];
                part1[1][c8 * 8 + cc][ks] = a1[cc];
            }
        } else if (red) {
            int t2 = tid - 256, jj = t2 & 15, ks = t2 >> 4;   // 16 j x 16 kslices
            #pragma unroll
            for (int g = 0; g < 5; ++g)
                #pragma unroll
                for (int b4 = 0; b4 < 4; ++b4) acc[g][b4] = 0.f;
            const uint4* wb = (const uint4*)WBb + ((size_t)(jgw * 640 + ks * 32) * 16) + jj;
            #pragma unroll 4
            for (int i = 0; i < 32; ++i) {
                uint4 wv = wb[(size_t)i * 16];          // 8 slots (5 real) = 16B
                float w0 = bf2f(wv.x & 0xFFFF), w1 = bf2f(wv.x >> 16);
                float w2 = bf2f(wv.y & 0xFFFF), w3 = bf2f(wv.y >> 16);
                float w4 = bf2f(wv.z & 0xFFFF);
                int k = ks * 32 + i;
                float x0 = xs2[0][k], x1 = xs2[1][k], x2 = xs2[2][k], x3 = xs2[3][k];
                acc[0][0] += x0 * w0; acc[1][0] += x0 * w1; acc[2][0] += x0 * w2; acc[3][0] += x0 * w3; acc[4][0] += x0 * w4;
                acc[0][1] += x1 * w0; acc[1][1] += x1 * w1; acc[2][1] += x1 * w2; acc[3][1] += x1 * w3; acc[4][1] += x1 * w4;
                acc[0][2] += x2 * w0; acc[1][2] += x2 * w1; acc[2][2] += x2 * w2; acc[3][2] += x2 * w3; acc[4][2] += x2 * w4;
                acc[0][3] += x3 * w0; acc[1][3] += x3 * w1; acc[2][3] += x3 * w2; acc[3][3] += x3 * w3; acc[4][3] += x3 * w4;
            }
        }
        __syncthreads();

        // ============ P1 reduce + tracker LSTM ============
        if (tid < 128) {
            int b = tid & 1, col = tid >> 1;
            float s = 0.f;
            #pragma unroll
            for (int ks = 0; ks < 32; ++ks) s += part1[b][col][ks];
            if (t > 0) s += blA[jg * 64 + col];
            gsum[b][col] = s;
        }
        __syncthreads();
        if (tid < 32) {
            int bl_ = tid >> 4, jj = tid & 15;
            int b = bg1 * 2 + bl_;
            int j = jg * 16 + jj;
            float4 g4 = *(const float4*)&gsum[bl_][jj * 4];     // a,i,f,o
            float tco = tc[((size_t)par * NB + b) * TKN + j];
            float c2v = tanhf(g4.x) * sigf(g4.y) + sigf(g4.z) * tco;
            float h2 = sigf(g4.w) * tanhf(c2v);
            tc[((size_t)(par ^ 1) * NB + b) * TKN + j] = c2v;
            cohSt(&th[((size_t)(par ^ 1) * NB + b) * TKN + j], h2);
        }
        gbar(slots, flag, ph);   // barrier A: th2 visible

        if (red) {
            // ============ WT part (K=128) + reduce + TreeLSTM ============
            {
                int b4 = tid >> 7, kk = tid & 127;
                xst[b4][kk] = cohLd(&th[((size_t)(par ^ 1) * NB + bg2 * 4 + b4) * TKN + kk]);
            }
            __syncthreads();
            if (w >= 4) {
                int t2 = tid - 256, jj = t2 & 15, ks = t2 >> 4;
                const uint4* wb = (const uint4*)WBb + ((size_t)(jgw * 640 + 512 + ks * 8) * 16) + jj;
                #pragma unroll
                for (int i = 0; i < 8; ++i) {
                    uint4 wv = wb[(size_t)i * 16];
                    float w0 = bf2f(wv.x & 0xFFFF), w1 = bf2f(wv.x >> 16);
                    float w2 = bf2f(wv.y & 0xFFFF), w3 = bf2f(wv.y >> 16);
                    float w4 = bf2f(wv.z & 0xFFFF);
                    int kk2 = ks * 8 + i;
                    float x0 = xst[0][kk2], x1 = xst[1][kk2], x2 = xst[2][kk2], x3 = xst[3][kk2];
                    acc[0][0] += x0 * w0; acc[1][0] += x0 * w1; acc[2][0] += x0 * w2; acc[3][0] += x0 * w3; acc[4][0] += x0 * w4;
                    acc[0][1] += x1 * w0; acc[1][1] += x1 * w1; acc[2][1] += x1 * w2; acc[3][1] += x1 * w3; acc[4][1] += x1 * w4;
                    acc[0][2] += x2 * w0; acc[1][2] += x2 * w1; acc[2][2] += x2 * w2; acc[3][2] += x2 * w3; acc[4][2] += x2 * w4;
                    acc[0][3] += x3 * w0; acc[1][3] += x3 * w1; acc[2][3] += x3 * w2; acc[3][3] += x3 * w3; acc[4][3] += x3 * w4;
                }
                #pragma unroll
                for (int g = 0; g < 5; ++g)
                    #pragma unroll
                    for (int b4 = 0; b4 < 4; ++b4)
                        part2[ks][jj][g * 4 + b4] = acc[g][b4];
            }
            __syncthreads();
            if (tid < 320) {
                int g = tid >> 6, r = tid & 63;
                int bl_ = r >> 4, jj = r & 15;
                float s = 0.f;
                #pragma unroll
                for (int ks = 0; ks < 16; ++ks) s += part2[ks][jj][g * 4 + bl_];
                gsum2[bl_][g][jj] = s;
            }
            __syncthreads();
            if (tid < 64) {
                int bl_ = tid >> 4, jj = tid & 15;
                int b = bg2 * 4 + bl_;
                int wk = wkA[t * NB + b];
                if (wk >= 0) {
                    int j = jgw * 16 + jj;
                    float ga  = gsum2[bl_][0][jj] + bLv[0 * 256 + j];
                    float gi  = gsum2[bl_][1][jj] + bLv[1 * 256 + j];
                    float gf1 = gsum2[bl_][2][jj] + bLv[2 * 256 + j];
                    float gf2 = gsum2[bl_][3][jj] + bLv[3 * 256 + j];
                    float go  = gsum2[bl_][4][jj] + bLv[4 * 256 + j];
                    int c1 = s1code[t * NB + b], c2 = s2code[t * NB + b];
                    float s2cv = (c2 == -1) ? 0.f
                                : ((c2 >= 1000) ? redc[((size_t)(c2 - 1000) * NB + b) * DN + j]
                                                : bufc[((size_t)b * LN + c2) * DN + j]);
                    float s1cv = (c1 == -1) ? 0.f
                                : ((c1 >= 1000) ? redc[((size_t)(c1 - 1000) * NB + b) * DN + j]
                                                : bufc[((size_t)b * LN + c1) * DN + j]);
                    float cc = tanhf(ga) * sigf(gi) + sigf(gf1) * s2cv + sigf(gf2) * s1cv;
                    float hh = sigf(go) * tanhf(cc);
                    cohSt(&redh[((size_t)wk * NB + b) * DN + j], hh);   // cross-WG
                    redc[((size_t)wk * NB + b) * DN + j] = cc;          // owner-stable
                }
            }
            gbar(slots, flag, ph);   // barrier C: redh visible
        }
    }

    // ===== final output: P2-owner (b,j) writes its slice =====
    if (tid < 64) {
        int bl_ = tid >> 4, jj = tid & 15;
        int b = bg2 * 4 + bl_;
        int j = jgw * 16 + jj;
        int c = fcode[b];
        float h = 0.f, cv = 0.f;
        if (c >= 1000) {
            h  = cohLd(&redh[((size_t)(c - 1000) * NB + b) * DN + j]);
            cv = redc[((size_t)(c - 1000) * NB + b) * DN + j];
        } else if (c >= 0) {
            h  = bufh[((size_t)b * LN + c) * DN + j];
            cv = bufc[((size_t)b * LN + c) * DN + j];
        }
        out[(size_t)b * 2 * DN + j]      = h;
        out[(size_t)b * 2 * DN + DN + j] = cv;
    }
}

extern "C" void kernel_launch(void* const* d_in, const int* in_sizes, int n_in,
                              void* d_out, int out_size, void* d_ws, size_t ws_size,
                              hipStream_t stream) {
    const float* bufh = (const float*)d_in[0];
    const float* bufc = (const float*)d_in[1];
    const float* Wb   = (const float*)d_in[2];
    const float* W1   = (const float*)d_in[3];
    const float* W2   = (const float*)d_in[4];
    const float* Wl   = (const float*)d_in[5];
    const float* blv  = (const float*)d_in[6];
    const float* WLm  = (const float*)d_in[7];
    const float* bLv  = (const float*)d_in[8];
    const float* WR   = (const float*)d_in[9];
    const float* WT   = (const float*)d_in[10];
    const int* trans  = (const int*)d_in[11];
    float* out = (float*)d_out;

    char* p = (char*)d_ws;
    auto carve = [&](size_t bytes) -> char* {
        char* r = p;
        p += (bytes + 255) & ~(size_t)255;
        return r;
    };
    int* tbcode = (int*)carve((size_t)TN * NB * 4);
    int* s1code = (int*)carve((size_t)TN * NB * 4);
    int* s2code = (int*)carve((size_t)TN * NB * 4);
    int* wkA    = (int*)carve((size_t)TN * NB * 4);
    int* fcode  = (int*)carve((size_t)NB * 4);
    int* anyred = (int*)carve((size_t)TN * 4);
    float* th   = (float*)carve((size_t)2 * NB * TKN * 4);
    float* tc   = (float*)carve((size_t)2 * NB * TKN * 4);
    float* redh = (float*)carve((size_t)RMAX * NB * DN * 4);
    float* redc = (float*)carve((size_t)RMAX * NB * DN * 4);
    unsigned short* WAb = (unsigned short*)carve((size_t)8 * 896 * 64 * 2);
    float* blA  = (float*)carve((size_t)512 * 4);
    unsigned short* WBb = (unsigned short*)carve((size_t)16 * 640 * 128 * 2);
    unsigned* slots = (unsigned*)carve((size_t)NWG * 16 * 4);
    unsigned* flag  = (unsigned*)carve(256);

    hipMemsetAsync(th, 0, (size_t)2 * NB * TKN * 4, stream);
    hipMemsetAsync(tc, 0, (size_t)2 * NB * TKN * 4, stream);
    hipMemsetAsync(slots, 0, (size_t)NWG * 16 * 4, stream);
    hipMemsetAsync(flag, 0, 256, stream);

    k_sched<<<1, 64, 0, stream>>>(trans, tbcode, s1code, s2code, wkA, fcode, anyred);
    k_pack_a<<<(8 * 896 * 64 + 255) / 256, 256, 0, stream>>>(Wb, W1, W2, Wl, blv, WAb, blA);
    k_pack_b<<<(16 * 640 * 128 + 255) / 256, 256, 0, stream>>>(WLm, WR, WT, WBb);
    k_spinn<<<NWG, NT, 0, stream>>>(bufh, bufc, WAb, blA, WBb, bLv,
                                    tbcode, s1code, s2code, wkA, fcode, anyred,
                                    th, tc, redh, redc, slots, flag, out);
}